// Round 3
// baseline (55.926 us; speedup 1.0000x reference)
//
#include <hip/hip_runtime.h>

// Problem constants (fixed by the reference)
constexpr int N    = 16384;
constexpr int K    = 32;
constexpr int D    = 128;
constexpr int SPAD = K + 4;       // padded LDS row (36) to break bank conflicts

// ------------------------------------------------------------------
// Stage 1: per-block partial E_b = T_b - S_b * c  -> ws[block][K*D]
// ROWS=16 rows per block, grid = N/16 = 1024 blocks (~4 blocks/CU).
// ------------------------------------------------------------------
constexpr int ROWS1 = 16;
constexpr int GRID1 = N / ROWS1;  // 1024

__global__ __launch_bounds__(256) void enc_partial(
    const float* __restrict__ x,      // (N, D)
    const float* __restrict__ codes,  // (K, D)
    const float* __restrict__ scale,  // (K,)
    float* __restrict__ ws)           // (GRID1, K*D)
{
    __shared__ float sc_lds[ROWS1][SPAD];  // raw scores l2*scale
    __shared__ float w_lds[ROWS1][SPAD];   // softmax weights

    const int tid = threadIdx.x;
    const int k   = tid >> 3;   // 0..31  (codeword owned by this thread)
    const int dc  = tid & 7;    // 0..7   (d-chunk owned)
    const int d0  = dc << 4;    // 16 floats per chunk

    // codes fragment for (k, d0..d0+15) in registers for the whole kernel
    const float4 ck0 = *reinterpret_cast<const float4*>(&codes[k * D + d0 + 0]);
    const float4 ck1 = *reinterpret_cast<const float4*>(&codes[k * D + d0 + 4]);
    const float4 ck2 = *reinterpret_cast<const float4*>(&codes[k * D + d0 + 8]);
    const float4 ck3 = *reinterpret_cast<const float4*>(&codes[k * D + d0 + 12]);
    const float scl = scale[k];

    const float* xb = x + (long)blockIdx.x * ROWS1 * D + d0;

    // ---------------- Phase 1: scores[n][k] = ||x_n - c_k|| * scale[k] ----------------
    #pragma unroll 4
    for (int n = 0; n < ROWS1; ++n) {
        const float4* xr = reinterpret_cast<const float4*>(xb + (long)n * D);
        float4 x0 = xr[0], x1 = xr[1], x2 = xr[2], x3 = xr[3];
        float p = 0.f, r;
        r = x0.x - ck0.x; p = fmaf(r, r, p);
        r = x0.y - ck0.y; p = fmaf(r, r, p);
        r = x0.z - ck0.z; p = fmaf(r, r, p);
        r = x0.w - ck0.w; p = fmaf(r, r, p);
        r = x1.x - ck1.x; p = fmaf(r, r, p);
        r = x1.y - ck1.y; p = fmaf(r, r, p);
        r = x1.z - ck1.z; p = fmaf(r, r, p);
        r = x1.w - ck1.w; p = fmaf(r, r, p);
        r = x2.x - ck2.x; p = fmaf(r, r, p);
        r = x2.y - ck2.y; p = fmaf(r, r, p);
        r = x2.z - ck2.z; p = fmaf(r, r, p);
        r = x2.w - ck2.w; p = fmaf(r, r, p);
        r = x3.x - ck3.x; p = fmaf(r, r, p);
        r = x3.y - ck3.y; p = fmaf(r, r, p);
        r = x3.z - ck3.z; p = fmaf(r, r, p);
        r = x3.w - ck3.w; p = fmaf(r, r, p);
        // reduce over the 8 contiguous lanes sharing this k
        p += __shfl_xor(p, 1);
        p += __shfl_xor(p, 2);
        p += __shfl_xor(p, 4);
        if (dc == 0) sc_lds[n][k] = sqrtf(p) * scl;
    }
    __syncthreads();

    // ---------------- Softmax over K per row: 16 threads/row, 2 k's each ----------------
    {
        const int row = tid >> 4;      // 0..15
        const int q   = tid & 15;
        float s0 = sc_lds[row][q];
        float s1 = sc_lds[row][q + 16];
        float m = fmaxf(s0, s1);
        m = fmaxf(m, __shfl_xor(m, 1));
        m = fmaxf(m, __shfl_xor(m, 2));
        m = fmaxf(m, __shfl_xor(m, 4));
        m = fmaxf(m, __shfl_xor(m, 8));
        const float LOG2E = 1.44269504088896f;
        float e0 = exp2f((s0 - m) * LOG2E);
        float e1 = exp2f((s1 - m) * LOG2E);
        float sum = e0 + e1;
        sum += __shfl_xor(sum, 1);
        sum += __shfl_xor(sum, 2);
        sum += __shfl_xor(sum, 4);
        sum += __shfl_xor(sum, 8);
        float inv = 1.0f / sum;
        w_lds[row][q]      = e0 * inv;
        w_lds[row][q + 16] = e1 * inv;
    }
    __syncthreads();

    // ---------------- Phase 2: T[k,d] = sum_n w*x ; S[k] = sum_n w ----------------
    float4 t0 = make_float4(0.f, 0.f, 0.f, 0.f);
    float4 t1 = t0, t2 = t0, t3 = t0;
    float sw = 0.f;
    #pragma unroll 4
    for (int n = 0; n < ROWS1; ++n) {
        float w = w_lds[n][k];
        const float4* xr = reinterpret_cast<const float4*>(xb + (long)n * D);
        float4 x0 = xr[0], x1 = xr[1], x2 = xr[2], x3 = xr[3];
        t0.x = fmaf(w, x0.x, t0.x);
        t0.y = fmaf(w, x0.y, t0.y);
        t0.z = fmaf(w, x0.z, t0.z);
        t0.w = fmaf(w, x0.w, t0.w);
        t1.x = fmaf(w, x1.x, t1.x);
        t1.y = fmaf(w, x1.y, t1.y);
        t1.z = fmaf(w, x1.z, t1.z);
        t1.w = fmaf(w, x1.w, t1.w);
        t2.x = fmaf(w, x2.x, t2.x);
        t2.y = fmaf(w, x2.y, t2.y);
        t2.z = fmaf(w, x2.z, t2.z);
        t2.w = fmaf(w, x2.w, t2.w);
        t3.x = fmaf(w, x3.x, t3.x);
        t3.y = fmaf(w, x3.y, t3.y);
        t3.z = fmaf(w, x3.z, t3.z);
        t3.w = fmaf(w, x3.w, t3.w);
        sw += w;
    }

    // ---------------- Epilogue: partial E_b = T - S*c -> ws (plain stores) ----------------
    // Note: k*D + d0 == tid*16, so each thread's 16 floats are contiguous.
    float* o = ws + (long)blockIdx.x * (K * D) + tid * 16;
    float4 e0 = make_float4(t0.x - sw * ck0.x, t0.y - sw * ck0.y,
                            t0.z - sw * ck0.z, t0.w - sw * ck0.w);
    float4 e1 = make_float4(t1.x - sw * ck1.x, t1.y - sw * ck1.y,
                            t1.z - sw * ck1.z, t1.w - sw * ck1.w);
    float4 e2 = make_float4(t2.x - sw * ck2.x, t2.y - sw * ck2.y,
                            t2.z - sw * ck2.z, t2.w - sw * ck2.w);
    float4 e3 = make_float4(t3.x - sw * ck3.x, t3.y - sw * ck3.y,
                            t3.z - sw * ck3.z, t3.w - sw * ck3.w);
    reinterpret_cast<float4*>(o)[0] = e0;
    reinterpret_cast<float4*>(o)[1] = e1;
    reinterpret_cast<float4*>(o)[2] = e2;
    reinterpret_cast<float4*>(o)[3] = e3;
}

// ------------------------------------------------------------------
// Stage 2: column-sum ws[1024][4096] -> out[4096].
// Single-writer plain stores (no atomics, no pre-zero needed).
// Grid: 16 blocks; block b owns float4-columns [b*64, b*64+64).
// Thread layout: col = tid&63, slice = tid>>2 ... (4 slices x 256 rows),
// LDS-combine the 4 slice partials, slice 0 stores.
// ------------------------------------------------------------------
__global__ __launch_bounds__(256) void reduce_kernel(
    const float* __restrict__ ws, float* __restrict__ out)
{
    __shared__ float4 part[3][64];    // slices 1..3 park partials here

    const int tid   = threadIdx.x;
    const int col   = tid & 63;                  // float4-col within block
    const int slice = tid >> 6;                  // 0..3, 256 rows each
    const int gcol  = blockIdx.x * 64 + col;     // 0..1023 (float4 columns)

    const float4* P = reinterpret_cast<const float4*>(ws);  // [1024][1024]
    float4 acc = make_float4(0.f, 0.f, 0.f, 0.f);
    long base = (long)slice * 256 * 1024 + gcol;
    #pragma unroll 8
    for (int r = 0; r < 256; ++r) {
        float4 v = P[base + (long)r * 1024];
        acc.x += v.x; acc.y += v.y; acc.z += v.z; acc.w += v.w;
    }
    if (slice != 0) {
        part[slice - 1][col] = acc;
    }
    __syncthreads();
    if (slice == 0) {
        float4 a = part[0][col], b = part[1][col], c = part[2][col];
        acc.x += a.x + b.x + c.x;
        acc.y += a.y + b.y + c.y;
        acc.z += a.z + b.z + c.z;
        acc.w += a.w + b.w + c.w;
        reinterpret_cast<float4*>(out)[gcol] = acc;
    }
}

// ------------------------------------------------------------------
// Fallback (ws too small): direct-atomic kernel, 256 blocks.
// Needs out pre-zeroed (memset only on this path).
// ------------------------------------------------------------------
constexpr int ROWSF = 64;

__global__ __launch_bounds__(256) void enc_atomic(
    const float* __restrict__ x,
    const float* __restrict__ codes,
    const float* __restrict__ scale,
    float* __restrict__ out)
{
    __shared__ float sc_lds[ROWSF][SPAD];
    __shared__ float w_lds[ROWSF][SPAD];

    const int tid = threadIdx.x;
    const int k   = tid >> 3;
    const int dc  = tid & 7;
    const int d0  = dc << 4;

    const float4 ck0 = *reinterpret_cast<const float4*>(&codes[k * D + d0 + 0]);
    const float4 ck1 = *reinterpret_cast<const float4*>(&codes[k * D + d0 + 4]);
    const float4 ck2 = *reinterpret_cast<const float4*>(&codes[k * D + d0 + 8]);
    const float4 ck3 = *reinterpret_cast<const float4*>(&codes[k * D + d0 + 12]);
    const float scl = scale[k];

    const float* xb = x + (long)blockIdx.x * ROWSF * D + d0;

    #pragma unroll 4
    for (int n = 0; n < ROWSF; ++n) {
        const float4* xr = reinterpret_cast<const float4*>(xb + (long)n * D);
        float4 x0 = xr[0], x1 = xr[1], x2 = xr[2], x3 = xr[3];
        float p = 0.f, r;
        r = x0.x - ck0.x; p = fmaf(r, r, p);
        r = x0.y - ck0.y; p = fmaf(r, r, p);
        r = x0.z - ck0.z; p = fmaf(r, r, p);
        r = x0.w - ck0.w; p = fmaf(r, r, p);
        r = x1.x - ck1.x; p = fmaf(r, r, p);
        r = x1.y - ck1.y; p = fmaf(r, r, p);
        r = x1.z - ck1.z; p = fmaf(r, r, p);
        r = x1.w - ck1.w; p = fmaf(r, r, p);
        r = x2.x - ck2.x; p = fmaf(r, r, p);
        r = x2.y - ck2.y; p = fmaf(r, r, p);
        r = x2.z - ck2.z; p = fmaf(r, r, p);
        r = x2.w - ck2.w; p = fmaf(r, r, p);
        r = x3.x - ck3.x; p = fmaf(r, r, p);
        r = x3.y - ck3.y; p = fmaf(r, r, p);
        r = x3.z - ck3.z; p = fmaf(r, r, p);
        r = x3.w - ck3.w; p = fmaf(r, r, p);
        p += __shfl_xor(p, 1);
        p += __shfl_xor(p, 2);
        p += __shfl_xor(p, 4);
        if (dc == 0) sc_lds[n][k] = sqrtf(p) * scl;
    }
    __syncthreads();

    {
        const int row = tid >> 2;
        const int q   = tid & 3;
        float4 s0 = *reinterpret_cast<const float4*>(&sc_lds[row][q * 8 + 0]);
        float4 s1 = *reinterpret_cast<const float4*>(&sc_lds[row][q * 8 + 4]);
        float m = fmaxf(fmaxf(fmaxf(s0.x, s0.y), fmaxf(s0.z, s0.w)),
                        fmaxf(fmaxf(s1.x, s1.y), fmaxf(s1.z, s1.w)));
        m = fmaxf(m, __shfl_xor(m, 1));
        m = fmaxf(m, __shfl_xor(m, 2));
        const float LOG2E = 1.44269504088896f;
        float e0 = exp2f((s0.x - m) * LOG2E);
        float e1 = exp2f((s0.y - m) * LOG2E);
        float e2 = exp2f((s0.z - m) * LOG2E);
        float e3 = exp2f((s0.w - m) * LOG2E);
        float e4 = exp2f((s1.x - m) * LOG2E);
        float e5 = exp2f((s1.y - m) * LOG2E);
        float e6 = exp2f((s1.z - m) * LOG2E);
        float e7 = exp2f((s1.w - m) * LOG2E);
        float sum = ((e0 + e1) + (e2 + e3)) + ((e4 + e5) + (e6 + e7));
        sum += __shfl_xor(sum, 1);
        sum += __shfl_xor(sum, 2);
        float inv = 1.0f / sum;
        *reinterpret_cast<float4*>(&w_lds[row][q * 8 + 0]) =
            make_float4(e0 * inv, e1 * inv, e2 * inv, e3 * inv);
        *reinterpret_cast<float4*>(&w_lds[row][q * 8 + 4]) =
            make_float4(e4 * inv, e5 * inv, e6 * inv, e7 * inv);
    }
    __syncthreads();

    float4 t0 = make_float4(0.f, 0.f, 0.f, 0.f);
    float4 t1 = t0, t2 = t0, t3 = t0;
    float sw = 0.f;
    #pragma unroll 4
    for (int n = 0; n < ROWSF; ++n) {
        float w = w_lds[n][k];
        const float4* xr = reinterpret_cast<const float4*>(xb + (long)n * D);
        float4 x0 = xr[0], x1 = xr[1], x2 = xr[2], x3 = xr[3];
        t0.x = fmaf(w, x0.x, t0.x);
        t0.y = fmaf(w, x0.y, t0.y);
        t0.z = fmaf(w, x0.z, t0.z);
        t0.w = fmaf(w, x0.w, t0.w);
        t1.x = fmaf(w, x1.x, t1.x);
        t1.y = fmaf(w, x1.y, t1.y);
        t1.z = fmaf(w, x1.z, t1.z);
        t1.w = fmaf(w, x1.w, t1.w);
        t2.x = fmaf(w, x2.x, t2.x);
        t2.y = fmaf(w, x2.y, t2.y);
        t2.z = fmaf(w, x2.z, t2.z);
        t2.w = fmaf(w, x2.w, t2.w);
        t3.x = fmaf(w, x3.x, t3.x);
        t3.y = fmaf(w, x3.y, t3.y);
        t3.z = fmaf(w, x3.z, t3.z);
        t3.w = fmaf(w, x3.w, t3.w);
        sw += w;
    }

    float* o = out + k * D + d0;
    atomicAdd(&o[0],  t0.x - sw * ck0.x);
    atomicAdd(&o[1],  t0.y - sw * ck0.y);
    atomicAdd(&o[2],  t0.z - sw * ck0.z);
    atomicAdd(&o[3],  t0.w - sw * ck0.w);
    atomicAdd(&o[4],  t1.x - sw * ck1.x);
    atomicAdd(&o[5],  t1.y - sw * ck1.y);
    atomicAdd(&o[6],  t1.z - sw * ck1.z);
    atomicAdd(&o[7],  t1.w - sw * ck1.w);
    atomicAdd(&o[8],  t2.x - sw * ck2.x);
    atomicAdd(&o[9],  t2.y - sw * ck2.y);
    atomicAdd(&o[10], t2.z - sw * ck2.z);
    atomicAdd(&o[11], t2.w - sw * ck2.w);
    atomicAdd(&o[12], t3.x - sw * ck3.x);
    atomicAdd(&o[13], t3.y - sw * ck3.y);
    atomicAdd(&o[14], t3.z - sw * ck3.z);
    atomicAdd(&o[15], t3.w - sw * ck3.w);
}

extern "C" void kernel_launch(void* const* d_in, const int* in_sizes, int n_in,
                              void* d_out, int out_size, void* d_ws, size_t ws_size,
                              hipStream_t stream) {
    const float* x     = (const float*)d_in[0];
    const float* codes = (const float*)d_in[1];
    const float* scale = (const float*)d_in[2];
    float* out = (float*)d_out;

    const size_t ws_needed = (size_t)GRID1 * K * D * sizeof(float);  // 16 MB
    if (ws_size >= ws_needed) {
        float* ws = (float*)d_ws;
        enc_partial<<<GRID1, 256, 0, stream>>>(x, codes, scale, ws);
        reduce_kernel<<<16, 256, 0, stream>>>(ws, out);
    } else {
        hipMemsetAsync(out, 0, K * D * sizeof(float), stream);
        enc_atomic<<<N / ROWSF, 256, 0, stream>>>(x, codes, scale, out);
    }
}

// Round 4
// 28.867 us; speedup vs baseline: 1.9374x; 1.9374x over previous
//
#include <hip/hip_runtime.h>

// Problem constants (fixed by the reference)
constexpr int N    = 16384;
constexpr int K    = 32;
constexpr int D    = 128;
constexpr int SPAD = K + 4;       // padded LDS row (36) to break bank conflicts

// ------------------------------------------------------------------
// Stage 1: per-block partial E_b = T_b - S_b * c  -> ws[block][K*D]
// ROWS1=32 rows per block, grid = N/32 = 512 blocks (2 blocks/CU).
// x tile staged in LDS once (coalesced, no duplicated global reads).
// ------------------------------------------------------------------
constexpr int ROWS1 = 32;
constexpr int GRID1 = N / ROWS1;  // 512

__global__ __launch_bounds__(256) void enc_partial(
    const float* __restrict__ x,      // (N, D)
    const float* __restrict__ codes,  // (K, D)
    const float* __restrict__ scale,  // (K,)
    float* __restrict__ ws)           // (GRID1, K*D)
{
    __shared__ float xs[ROWS1][D];         // 16 KB x tile
    __shared__ float sc_lds[ROWS1][SPAD];  // raw scores l2*scale
    __shared__ float w_lds[ROWS1][SPAD];   // softmax weights

    const int tid = threadIdx.x;
    const int k   = tid >> 3;   // 0..31  (codeword owned by this thread)
    const int dc  = tid & 7;    // 0..7   (d-chunk owned)
    const int d0  = dc << 4;    // 16 floats per chunk

    // ---- stage x tile: 32 rows x 128 floats = 1024 float4, 4 per thread ----
    {
        const float4* xg = reinterpret_cast<const float4*>(x + (long)blockIdx.x * ROWS1 * D);
        float4* xs4 = reinterpret_cast<float4*>(&xs[0][0]);
        #pragma unroll
        for (int i = 0; i < 4; ++i)
            xs4[tid + i * 256] = xg[tid + i * 256];
    }

    // codes fragment for (k, d0..d0+15) in registers for the whole kernel
    const float4 ck0 = *reinterpret_cast<const float4*>(&codes[k * D + d0 + 0]);
    const float4 ck1 = *reinterpret_cast<const float4*>(&codes[k * D + d0 + 4]);
    const float4 ck2 = *reinterpret_cast<const float4*>(&codes[k * D + d0 + 8]);
    const float4 ck3 = *reinterpret_cast<const float4*>(&codes[k * D + d0 + 12]);
    const float scl = scale[k];

    __syncthreads();

    // ---------------- Phase 1: scores[n][k] = ||x_n - c_k|| * scale[k] ----------------
    #pragma unroll 4
    for (int n = 0; n < ROWS1; ++n) {
        const float4* xr = reinterpret_cast<const float4*>(&xs[n][d0]);
        float4 x0 = xr[0], x1 = xr[1], x2 = xr[2], x3 = xr[3];
        float p = 0.f, r;
        r = x0.x - ck0.x; p = fmaf(r, r, p);
        r = x0.y - ck0.y; p = fmaf(r, r, p);
        r = x0.z - ck0.z; p = fmaf(r, r, p);
        r = x0.w - ck0.w; p = fmaf(r, r, p);
        r = x1.x - ck1.x; p = fmaf(r, r, p);
        r = x1.y - ck1.y; p = fmaf(r, r, p);
        r = x1.z - ck1.z; p = fmaf(r, r, p);
        r = x1.w - ck1.w; p = fmaf(r, r, p);
        r = x2.x - ck2.x; p = fmaf(r, r, p);
        r = x2.y - ck2.y; p = fmaf(r, r, p);
        r = x2.z - ck2.z; p = fmaf(r, r, p);
        r = x2.w - ck2.w; p = fmaf(r, r, p);
        r = x3.x - ck3.x; p = fmaf(r, r, p);
        r = x3.y - ck3.y; p = fmaf(r, r, p);
        r = x3.z - ck3.z; p = fmaf(r, r, p);
        r = x3.w - ck3.w; p = fmaf(r, r, p);
        // reduce over the 8 contiguous lanes sharing this k
        p += __shfl_xor(p, 1);
        p += __shfl_xor(p, 2);
        p += __shfl_xor(p, 4);
        if (dc == 0) sc_lds[n][k] = sqrtf(p) * scl;
    }
    __syncthreads();

    // ---------------- Softmax over K per row: 8 threads/row, 4 k's each ----------------
    {
        const int row = tid >> 3;      // 0..31
        const int q   = tid & 7;
        float s0 = sc_lds[row][q];
        float s1 = sc_lds[row][q + 8];
        float s2 = sc_lds[row][q + 16];
        float s3 = sc_lds[row][q + 24];
        float m = fmaxf(fmaxf(s0, s1), fmaxf(s2, s3));
        m = fmaxf(m, __shfl_xor(m, 1));
        m = fmaxf(m, __shfl_xor(m, 2));
        m = fmaxf(m, __shfl_xor(m, 4));
        const float LOG2E = 1.44269504088896f;
        float e0 = exp2f((s0 - m) * LOG2E);
        float e1 = exp2f((s1 - m) * LOG2E);
        float e2 = exp2f((s2 - m) * LOG2E);
        float e3 = exp2f((s3 - m) * LOG2E);
        float sum = (e0 + e1) + (e2 + e3);
        sum += __shfl_xor(sum, 1);
        sum += __shfl_xor(sum, 2);
        sum += __shfl_xor(sum, 4);
        float inv = 1.0f / sum;
        w_lds[row][q]      = e0 * inv;
        w_lds[row][q + 8]  = e1 * inv;
        w_lds[row][q + 16] = e2 * inv;
        w_lds[row][q + 24] = e3 * inv;
    }
    __syncthreads();

    // ---------------- Phase 2: T[k,d] = sum_n w*x ; S[k] = sum_n w ----------------
    float4 t0 = make_float4(0.f, 0.f, 0.f, 0.f);
    float4 t1 = t0, t2 = t0, t3 = t0;
    float sw = 0.f;
    #pragma unroll 4
    for (int n = 0; n < ROWS1; ++n) {
        float w = w_lds[n][k];
        const float4* xr = reinterpret_cast<const float4*>(&xs[n][d0]);
        float4 x0 = xr[0], x1 = xr[1], x2 = xr[2], x3 = xr[3];
        t0.x = fmaf(w, x0.x, t0.x);
        t0.y = fmaf(w, x0.y, t0.y);
        t0.z = fmaf(w, x0.z, t0.z);
        t0.w = fmaf(w, x0.w, t0.w);
        t1.x = fmaf(w, x1.x, t1.x);
        t1.y = fmaf(w, x1.y, t1.y);
        t1.z = fmaf(w, x1.z, t1.z);
        t1.w = fmaf(w, x1.w, t1.w);
        t2.x = fmaf(w, x2.x, t2.x);
        t2.y = fmaf(w, x2.y, t2.y);
        t2.z = fmaf(w, x2.z, t2.z);
        t2.w = fmaf(w, x2.w, t2.w);
        t3.x = fmaf(w, x3.x, t3.x);
        t3.y = fmaf(w, x3.y, t3.y);
        t3.z = fmaf(w, x3.z, t3.z);
        t3.w = fmaf(w, x3.w, t3.w);
        sw += w;
    }

    // ---------------- Epilogue: partial E_b = T - S*c -> ws (plain stores) ----------------
    // Note: k*D + d0 == tid*16, so each thread's 16 floats are contiguous.
    float* o = ws + (long)blockIdx.x * (K * D) + tid * 16;
    reinterpret_cast<float4*>(o)[0] = make_float4(t0.x - sw * ck0.x, t0.y - sw * ck0.y,
                                                  t0.z - sw * ck0.z, t0.w - sw * ck0.w);
    reinterpret_cast<float4*>(o)[1] = make_float4(t1.x - sw * ck1.x, t1.y - sw * ck1.y,
                                                  t1.z - sw * ck1.z, t1.w - sw * ck1.w);
    reinterpret_cast<float4*>(o)[2] = make_float4(t2.x - sw * ck2.x, t2.y - sw * ck2.y,
                                                  t2.z - sw * ck2.z, t2.w - sw * ck2.w);
    reinterpret_cast<float4*>(o)[3] = make_float4(t3.x - sw * ck3.x, t3.y - sw * ck3.y,
                                                  t3.z - sw * ck3.z, t3.w - sw * ck3.w);
}

// ------------------------------------------------------------------
// Stage 2: column-sum ws[512][4096] -> out[4096].
// 256 blocks; block owns 4 float4-columns x all 512 rows.
// Thread: col = tid&3, slice = tid>>2 (64 slices x 8 rows).
// LDS-combine 64 slice partials per column; tid<4 store. No atomics.
// ------------------------------------------------------------------
__global__ __launch_bounds__(256) void reduce2(
    const float* __restrict__ ws, float* __restrict__ out)
{
    __shared__ float4 part[64][4];     // 4 KB

    const int tid   = threadIdx.x;
    const int col   = tid & 3;                   // f4-col within block
    const int slice = tid >> 2;                  // 0..63, 8 rows each
    const int gcol  = blockIdx.x * 4 + col;      // 0..1023 (float4 columns)

    const float4* P = reinterpret_cast<const float4*>(ws);  // [512][1024]
    float4 acc = make_float4(0.f, 0.f, 0.f, 0.f);
    #pragma unroll
    for (int r = 0; r < 8; ++r) {
        float4 v = P[(long)(slice * 8 + r) * 1024 + gcol];
        acc.x += v.x; acc.y += v.y; acc.z += v.z; acc.w += v.w;
    }
    part[slice][col] = acc;
    __syncthreads();

    // tree-reduce the 64 slices per column
    #pragma unroll
    for (int stride = 32; stride >= 1; stride >>= 1) {
        if (slice < stride && col == (tid & 3)) {
            if (tid < stride * 4) {
                float4 a = part[slice][col];
                float4 b = part[slice + stride][col];
                a.x += b.x; a.y += b.y; a.z += b.z; a.w += b.w;
                part[slice][col] = a;
            }
        }
        __syncthreads();
    }
    if (tid < 4) {
        reinterpret_cast<float4*>(out)[blockIdx.x * 4 + tid] = part[0][tid];
    }
}

// ------------------------------------------------------------------
// Fallback (ws too small): direct-atomic kernel, 256 blocks.
// Needs out pre-zeroed (memset only on this path).
// ------------------------------------------------------------------
constexpr int ROWSF = 64;

__global__ __launch_bounds__(256) void enc_atomic(
    const float* __restrict__ x,
    const float* __restrict__ codes,
    const float* __restrict__ scale,
    float* __restrict__ out)
{
    __shared__ float sc_lds[ROWSF][SPAD];
    __shared__ float w_lds[ROWSF][SPAD];

    const int tid = threadIdx.x;
    const int k   = tid >> 3;
    const int dc  = tid & 7;
    const int d0  = dc << 4;

    const float4 ck0 = *reinterpret_cast<const float4*>(&codes[k * D + d0 + 0]);
    const float4 ck1 = *reinterpret_cast<const float4*>(&codes[k * D + d0 + 4]);
    const float4 ck2 = *reinterpret_cast<const float4*>(&codes[k * D + d0 + 8]);
    const float4 ck3 = *reinterpret_cast<const float4*>(&codes[k * D + d0 + 12]);
    const float scl = scale[k];

    const float* xb = x + (long)blockIdx.x * ROWSF * D + d0;

    #pragma unroll 4
    for (int n = 0; n < ROWSF; ++n) {
        const float4* xr = reinterpret_cast<const float4*>(xb + (long)n * D);
        float4 x0 = xr[0], x1 = xr[1], x2 = xr[2], x3 = xr[3];
        float p = 0.f, r;
        r = x0.x - ck0.x; p = fmaf(r, r, p);
        r = x0.y - ck0.y; p = fmaf(r, r, p);
        r = x0.z - ck0.z; p = fmaf(r, r, p);
        r = x0.w - ck0.w; p = fmaf(r, r, p);
        r = x1.x - ck1.x; p = fmaf(r, r, p);
        r = x1.y - ck1.y; p = fmaf(r, r, p);
        r = x1.z - ck1.z; p = fmaf(r, r, p);
        r = x1.w - ck1.w; p = fmaf(r, r, p);
        r = x2.x - ck2.x; p = fmaf(r, r, p);
        r = x2.y - ck2.y; p = fmaf(r, r, p);
        r = x2.z - ck2.z; p = fmaf(r, r, p);
        r = x2.w - ck2.w; p = fmaf(r, r, p);
        r = x3.x - ck3.x; p = fmaf(r, r, p);
        r = x3.y - ck3.y; p = fmaf(r, r, p);
        r = x3.z - ck3.z; p = fmaf(r, r, p);
        r = x3.w - ck3.w; p = fmaf(r, r, p);
        p += __shfl_xor(p, 1);
        p += __shfl_xor(p, 2);
        p += __shfl_xor(p, 4);
        if (dc == 0) sc_lds[n][k] = sqrtf(p) * scl;
    }
    __syncthreads();

    {
        const int row = tid >> 2;
        const int q   = tid & 3;
        float4 s0 = *reinterpret_cast<const float4*>(&sc_lds[row][q * 8 + 0]);
        float4 s1 = *reinterpret_cast<const float4*>(&sc_lds[row][q * 8 + 4]);
        float m = fmaxf(fmaxf(fmaxf(s0.x, s0.y), fmaxf(s0.z, s0.w)),
                        fmaxf(fmaxf(s1.x, s1.y), fmaxf(s1.z, s1.w)));
        m = fmaxf(m, __shfl_xor(m, 1));
        m = fmaxf(m, __shfl_xor(m, 2));
        const float LOG2E = 1.44269504088896f;
        float e0 = exp2f((s0.x - m) * LOG2E);
        float e1 = exp2f((s0.y - m) * LOG2E);
        float e2 = exp2f((s0.z - m) * LOG2E);
        float e3 = exp2f((s0.w - m) * LOG2E);
        float e4 = exp2f((s1.x - m) * LOG2E);
        float e5 = exp2f((s1.y - m) * LOG2E);
        float e6 = exp2f((s1.z - m) * LOG2E);
        float e7 = exp2f((s1.w - m) * LOG2E);
        float sum = ((e0 + e1) + (e2 + e3)) + ((e4 + e5) + (e6 + e7));
        sum += __shfl_xor(sum, 1);
        sum += __shfl_xor(sum, 2);
        float inv = 1.0f / sum;
        *reinterpret_cast<float4*>(&w_lds[row][q * 8 + 0]) =
            make_float4(e0 * inv, e1 * inv, e2 * inv, e3 * inv);
        *reinterpret_cast<float4*>(&w_lds[row][q * 8 + 4]) =
            make_float4(e4 * inv, e5 * inv, e6 * inv, e7 * inv);
    }
    __syncthreads();

    float4 t0 = make_float4(0.f, 0.f, 0.f, 0.f);
    float4 t1 = t0, t2 = t0, t3 = t0;
    float sw = 0.f;
    #pragma unroll 4
    for (int n = 0; n < ROWSF; ++n) {
        float w = w_lds[n][k];
        const float4* xr = reinterpret_cast<const float4*>(xb + (long)n * D);
        float4 x0 = xr[0], x1 = xr[1], x2 = xr[2], x3 = xr[3];
        t0.x = fmaf(w, x0.x, t0.x);
        t0.y = fmaf(w, x0.y, t0.y);
        t0.z = fmaf(w, x0.z, t0.z);
        t0.w = fmaf(w, x0.w, t0.w);
        t1.x = fmaf(w, x1.x, t1.x);
        t1.y = fmaf(w, x1.y, t1.y);
        t1.z = fmaf(w, x1.z, t1.z);
        t1.w = fmaf(w, x1.w, t1.w);
        t2.x = fmaf(w, x2.x, t2.x);
        t2.y = fmaf(w, x2.y, t2.y);
        t2.z = fmaf(w, x2.z, t2.z);
        t2.w = fmaf(w, x2.w, t2.w);
        t3.x = fmaf(w, x3.x, t3.x);
        t3.y = fmaf(w, x3.y, t3.y);
        t3.z = fmaf(w, x3.z, t3.z);
        t3.w = fmaf(w, x3.w, t3.w);
        sw += w;
    }

    float* o = out + k * D + d0;
    atomicAdd(&o[0],  t0.x - sw * ck0.x);
    atomicAdd(&o[1],  t0.y - sw * ck0.y);
    atomicAdd(&o[2],  t0.z - sw * ck0.z);
    atomicAdd(&o[3],  t0.w - sw * ck0.w);
    atomicAdd(&o[4],  t1.x - sw * ck1.x);
    atomicAdd(&o[5],  t1.y - sw * ck1.y);
    atomicAdd(&o[6],  t1.z - sw * ck1.z);
    atomicAdd(&o[7],  t1.w - sw * ck1.w);
    atomicAdd(&o[8],  t2.x - sw * ck2.x);
    atomicAdd(&o[9],  t2.y - sw * ck2.y);
    atomicAdd(&o[10], t2.z - sw * ck2.z);
    atomicAdd(&o[11], t2.w - sw * ck2.w);
    atomicAdd(&o[12], t3.x - sw * ck3.x);
    atomicAdd(&o[13], t3.y - sw * ck3.y);
    atomicAdd(&o[14], t3.z - sw * ck3.z);
    atomicAdd(&o[15], t3.w - sw * ck3.w);
}

extern "C" void kernel_launch(void* const* d_in, const int* in_sizes, int n_in,
                              void* d_out, int out_size, void* d_ws, size_t ws_size,
                              hipStream_t stream) {
    const float* x     = (const float*)d_in[0];
    const float* codes = (const float*)d_in[1];
    const float* scale = (const float*)d_in[2];
    float* out = (float*)d_out;

    const size_t ws_needed = (size_t)GRID1 * K * D * sizeof(float);  // 8 MB
    if (ws_size >= ws_needed) {
        float* ws = (float*)d_ws;
        enc_partial<<<GRID1, 256, 0, stream>>>(x, codes, scale, ws);
        reduce2<<<256, 256, 0, stream>>>(ws, out);
    } else {
        hipMemsetAsync(out, 0, K * D * sizeof(float), stream);
        enc_atomic<<<N / ROWSF, 256, 0, stream>>>(x, codes, scale, out);
    }
}